// Round 20
// baseline (364.612 us; speedup 1.0000x reference)
//
#include <hip/hip_runtime.h>
#include <hip/hip_bf16.h>

// Problem constants (from reference setup_inputs)
#define KK   27
#define MM   80000
#define NN   200000
#define INC  64
#define OUTC 128
#define RIN  48
#define ROUT 96

// output-row slices: 5000 slices x 40 rows; key = k*NSLICE + s (k-major)
#define SLICE   40
#define NSLICE  (NN / SLICE)          // 5000
#define NKEY    (KK * NSLICE)         // 135000

// counting-sort blocking (HBLK=10: ~1.6 entries/block/bucket -> less line sharing)
#define HEPB    8192
#define HBLK    ((MM + HEPB - 1) / HEPB)   // 10
#define ETOT    (KK * MM)             // 2,160,000

// padded bf16 feature row: 64 bf16 = 128 B = exactly 2 cache lines
#define FROW    64

// T-scan geometry (135000 elements)
#define SCHUNK  1024
#define NCB2    ((NKEY + SCHUNK - 1) / SCHUNK)   // 132

#define CHUNK   768                   // stage2 per-chunk entry capacity

typedef __attribute__((ext_vector_type(8))) short bf16x8;  // 8 bf16 = 4 VGPR
typedef __attribute__((ext_vector_type(4))) float f32x4;

__device__ __forceinline__ float bf2f(short s) {
    return __uint_as_float(((unsigned)(unsigned short)s) << 16);
}

// ---------------------------------------------------------------------------
// Fallback: single-pass atomic scatter (R1 kernel, known-good, ~1.66 ms)
// ---------------------------------------------------------------------------
#define FB_BLOCKS_PER_K 200
#define FB_ENTRIES_PER_BLOCK ((MM + FB_BLOCKS_PER_K - 1) / FB_BLOCKS_PER_K)

__global__ __launch_bounds__(192)
void sparse_conv_scatter(const float* __restrict__ feat,
                         const float* __restrict__ w,
                         const int* __restrict__ imap,
                         const int* __restrict__ omap,
                         float* __restrict__ out)
{
    __shared__ float wlds[RIN * ROUT];
    const int k = blockIdx.y;
    const float* wk = w + (size_t)k * INC * OUTC;
    for (int idx = threadIdx.x; idx < RIN * ROUT; idx += 192) {
        int i = idx / ROUT;
        int o = idx - i * ROUT;
        wlds[idx] = wk[i * OUTC + o];
    }
    __syncthreads();

    const int sub = threadIdx.x / 96;
    const int oc  = threadIdx.x % 96;
    const int m0 = blockIdx.x * FB_ENTRIES_PER_BLOCK;
    const int m1 = min(m0 + FB_ENTRIES_PER_BLOCK, MM);
    const int* imk = imap + (size_t)k * MM;
    const int* omk = omap + (size_t)k * MM;

    for (int m = m0 + sub; m < m1; m += 2) {
        const int fin  = imk[m];
        const int fout = omk[m];
        const float4* f4 = (const float4*)(feat + (size_t)fin * RIN);
        float acc = 0.f;
        #pragma unroll
        for (int i4 = 0; i4 < RIN / 4; ++i4) {
            float4 v = f4[i4];
            acc += v.x * wlds[(i4 * 4 + 0) * ROUT + oc];
            acc += v.y * wlds[(i4 * 4 + 1) * ROUT + oc];
            acc += v.z * wlds[(i4 * 4 + 2) * ROUT + oc];
            acc += v.w * wlds[(i4 * 4 + 3) * ROUT + oc];
        }
        atomicAdd(&out[(size_t)fout * ROUT + oc], acc);
    }
}

// ---------------------------------------------------------------------------
// Precompute: features -> bf16 rows PADDED to 128B (zeros in cols 48..63),
// weights -> MFMA B-fragment pack
// ---------------------------------------------------------------------------
__global__ __launch_bounds__(256)
void feat_to_bf16(const float* __restrict__ f, __hip_bfloat16* __restrict__ fb)
{
    const size_t i = (size_t)blockIdx.x * 256 + threadIdx.x;   // one per 8 bf16 out
    if (i >= (size_t)NN * FROW / 8) return;
    const int row = (int)(i >> 3);
    const int c8  = (int)(i & 7);           // 8-bf16 group within padded row
    union { __hip_bfloat16 h[8]; uint4 v; } o;
    if (c8 < 6) {
        const float4* p = (const float4*)(f + (size_t)row * RIN + c8 * 8);
        float4 a = p[0], b = p[1];
        o.h[0] = __float2bfloat16(a.x);
        o.h[1] = __float2bfloat16(a.y);
        o.h[2] = __float2bfloat16(a.z);
        o.h[3] = __float2bfloat16(a.w);
        o.h[4] = __float2bfloat16(b.x);
        o.h[5] = __float2bfloat16(b.y);
        o.h[6] = __float2bfloat16(b.z);
        o.h[7] = __float2bfloat16(b.w);
    } else {
        o.v = make_uint4(0, 0, 0, 0);       // zero pad (k=48..63)
    }
    ((uint4*)fb)[i] = o.v;
}

// wpack: frag f = oct*2 + ktile of kernel k at ((k*12 + f)*64 + lane)*16 bytes
__global__ __launch_bounds__(64)
void build_wpack(const float* __restrict__ w, __hip_bfloat16* __restrict__ wp)
{
    const int b = blockIdx.x;          // k*12 + f
    const int k = b / 12;
    const int f = b % 12;
    const int oct = f / 2, ktile = f % 2;
    const int lane = threadIdx.x;
    const int oc    = oct * 16 + (lane & 15);
    const int kbase = ktile * 32 + (lane >> 4) * 8;
    union { __hip_bfloat16 h[8]; uint4 v; } o;
    #pragma unroll
    for (int j = 0; j < 8; ++j) {
        int ki = kbase + j;
        float val = (ki < RIN) ? w[(size_t)k * INC * OUTC + (size_t)ki * OUTC + oc] : 0.f;
        o.h[j] = __float2bfloat16(val);
    }
    ((uint4*)wp)[(size_t)b * 64 + lane] = o.v;
}

// ---------------------------------------------------------------------------
// Counting sort pass 1: per-(k,block) LDS histogram over slices.
// L layout: L[(k*HBLK + blk)*NSLICE + s]  -> COALESCED writes.
// ---------------------------------------------------------------------------
__global__ __launch_bounds__(256)
void hist_pass(const int* __restrict__ omap, int* __restrict__ L)
{
    __shared__ int h[NSLICE];          // 20 KB
    const int k = blockIdx.y;
    const int blk = blockIdx.x;
    for (int i = threadIdx.x; i < NSLICE; i += 256) h[i] = 0;
    __syncthreads();

    #pragma unroll
    for (int it = 0; it < HEPB / 256; ++it) {
        const int m = blk * HEPB + it * 256 + threadIdx.x;
        if (m < MM) atomicAdd(&h[omap[(size_t)k * MM + m] / SLICE], 1);  // LDS int
    }
    __syncthreads();
    int* row = L + ((size_t)k * HBLK + blk) * NSLICE;
    for (int i = threadIdx.x; i < NSLICE; i += 256) row[i] = h[i];
}

// ---------------------------------------------------------------------------
// blk_scan: per (k,s) column, exclusive prefix over the HBLK blocks (in place)
// and emit bucket total T[k*NSLICE + s]. All accesses coalesced across s.
// ---------------------------------------------------------------------------
__global__ __launch_bounds__(256)
void blk_scan(int* __restrict__ L, int* __restrict__ T)
{
    const int k = blockIdx.y;
    const int s = blockIdx.x * 256 + threadIdx.x;
    if (s >= NSLICE) return;
    int run = 0;
    #pragma unroll
    for (int blk = 0; blk < HBLK; ++blk) {
        const size_t idx = ((size_t)k * HBLK + blk) * NSLICE + s;
        const int v = L[idx];
        L[idx] = run;          // within-(k,s) exclusive offset
        run += v;
    }
    T[(size_t)k * NSLICE + s] = run;   // bucket total
}

// ---------------------------------------------------------------------------
// Generic flat exclusive scan of T[n] (3 kernels). scan_finalG also writes
// the sentinel T[n] = total.
// ---------------------------------------------------------------------------
__global__ __launch_bounds__(256)
void scan_partG(const int* __restrict__ T, int* __restrict__ S, int n)
{
    __shared__ int sh[256];
    const int t = threadIdx.x;
    const int base = blockIdx.x * SCHUNK + t * 4;
    int s = 0;
    #pragma unroll
    for (int j = 0; j < 4; ++j)
        if (base + j < n) s += T[base + j];
    sh[t] = s;
    __syncthreads();
    for (int off = 128; off > 0; off >>= 1) {
        if (t < off) sh[t] += sh[t + off];
        __syncthreads();
    }
    if (t == 0) S[blockIdx.x] = sh[0];
}

__global__ __launch_bounds__(256)
void scan_midG(int* __restrict__ S, int ncb)
{
    __shared__ int sh[256];
    const int t = threadIdx.x;
    const int per = (ncb + 255) / 256;
    const int lo = t * per;
    const int hi = min(lo + per, ncb);
    int tot = 0;
    for (int i = lo; i < hi; ++i) tot += S[i];
    sh[t] = tot;
    __syncthreads();
    for (int off = 1; off < 256; off <<= 1) {
        int x = (t >= off) ? sh[t - off] : 0;
        __syncthreads();
        sh[t] += x;
        __syncthreads();
    }
    int run = sh[t] - tot;    // exclusive base
    for (int i = lo; i < hi; ++i) { const int v = S[i]; S[i] = run; run += v; }
}

__global__ __launch_bounds__(256)
void scan_finalG(int* __restrict__ T, const int* __restrict__ S, int n, int total)
{
    __shared__ int sh[256];
    const int t = threadIdx.x;
    const int base = blockIdx.x * SCHUNK + t * 4;
    int v[4];
    int s = 0;
    #pragma unroll
    for (int j = 0; j < 4; ++j) {
        v[j] = (base + j < n) ? T[base + j] : 0;
        s += v[j];
    }
    sh[t] = s;
    __syncthreads();
    for (int off = 1; off < 256; off <<= 1) {
        int x = (t >= off) ? sh[t - off] : 0;
        __syncthreads();
        sh[t] += x;
        __syncthreads();
    }
    int run = sh[t] - s + S[blockIdx.x];
    #pragma unroll
    for (int j = 0; j < 4; ++j) {
        if (base + j < n) { T[base + j] = run; run += v[j]; }
    }
    if (blockIdx.x == 0 && t == 0) T[n] = total;   // sentinel
}

// ---------------------------------------------------------------------------
// Counting sort pass 2: scatter tagged entries. Per-block bucket bases
// (B[key] + within-key block offset) staged into LDS with COALESCED reads;
// rank from LDS int atomics. elist[slot] = fin | (lr << 18).
// ---------------------------------------------------------------------------
__global__ __launch_bounds__(256)
void write_elist(const int* __restrict__ omap,
                 const int* __restrict__ imap,
                 const int* __restrict__ B,
                 const int* __restrict__ L,
                 unsigned* __restrict__ elist)
{
    __shared__ int basev[NSLICE];      // 20 KB
    __shared__ int run[NSLICE];        // 20 KB
    const int k = blockIdx.y;
    const int blk = blockIdx.x;

    const int* Bk = B + (size_t)k * NSLICE;
    const int* Lk = L + ((size_t)k * HBLK + blk) * NSLICE;
    for (int i = threadIdx.x; i < NSLICE; i += 256) {
        basev[i] = Bk[i] + Lk[i];      // global slot base for this block's run
        run[i] = 0;
    }
    __syncthreads();

    #pragma unroll
    for (int it = 0; it < HEPB / 256; ++it) {
        const int m = blk * HEPB + it * 256 + threadIdx.x;
        if (m < MM) {
            const size_t e = (size_t)k * MM + m;
            const int r = omap[e];
            const int s = r / SLICE;
            const int lr = r - s * SLICE;
            const int rank = atomicAdd(&run[s], 1);   // LDS int atomic
            elist[basev[s] + rank] = (unsigned)imap[e] | ((unsigned)lr << 18);
        }
    }
}

// ---------------------------------------------------------------------------
// Stage 1 (MFMA): per (range,k), stream the contiguous sorted segment as
// 16-entry x 96-oc tiles with DEPTH-2 prefetch; contrib written LINEARLY.
// Feature rows are 128B-aligned (2 lines exactly per gather).
// ---------------------------------------------------------------------------
__global__ __launch_bounds__(256)
void stage1_mfma(const __hip_bfloat16* __restrict__ fb,
                 const __hip_bfloat16* __restrict__ wp,
                 const unsigned* __restrict__ elist,
                 const int* __restrict__ B,
                 int t, int spr, int capseg,
                 __hip_bfloat16* __restrict__ contrib)
{
    const int k = blockIdx.y;
    const int wid  = threadIdx.x >> 6;
    const int lane = threadIdx.x & 63;
    const int lo = lane & 15, hi = lane >> 4;

    const size_t key0 = (size_t)k * NSLICE + (size_t)t * spr;
    const int seg0 = B[key0];
    const int seg1 = B[key0 + spr];          // sentinel covers the end
    const int n = seg1 - seg0;
    const int ntiles = (n + 15) >> 4;

    bf16x8 Bf[12];
    #pragma unroll
    for (int f = 0; f < 12; ++f)
        Bf[f] = *reinterpret_cast<const bf16x8*>(
            (const char*)wp + (((size_t)k * 12 + f) * 64 + lane) * 16);

    const int wstride = gridDim.x * 4;
    const int t0 = blockIdx.x * 4 + wid;
    if (t0 >= ntiles) return;

    auto LOADA = [&](int tile, bf16x8& a0, bf16x8& a1) {
        const int ea = seg0 + tile * 16 + lo;
        const unsigned tg = (tile < ntiles && ea < seg1) ? elist[ea] : 0u;
        const size_t rb = (size_t)(tg & 0x3FFFFu) * (FROW * 2);   // 128B rows
        a0 = *reinterpret_cast<const bf16x8*>((const char*)fb + rb + hi * 16);
        a1 = *reinterpret_cast<const bf16x8*>((const char*)fb + rb + 64 + hi * 16);
    };

    bf16x8 A0, A1, P0, P1, Q0, Q1;
    LOADA(t0, A0, A1);
    LOADA(t0 + wstride, P0, P1);

    for (int tile = t0; tile < ntiles; tile += wstride) {
        LOADA(tile + 2 * wstride, Q0, Q1);   // depth-2 prefetch

        const int e4 = tile * 16 + hi * 4;      // segment-local entry index base
        const size_t sbase = (size_t)k * capseg + e4;
        const bool v0 = (e4 + 0) < n, v1 = (e4 + 1) < n,
                   v2 = (e4 + 2) < n, v3 = (e4 + 3) < n;

        #pragma unroll
        for (int oct = 0; oct < 6; ++oct) {
            f32x4 a = {0.f, 0.f, 0.f, 0.f};
            a = __builtin_amdgcn_mfma_f32_16x16x32_bf16(A0, Bf[oct * 2 + 0], a, 0, 0, 0);
            a = __builtin_amdgcn_mfma_f32_16x16x32_bf16(A1, Bf[oct * 2 + 1], a, 0, 0, 0);
            const int oc = oct * 16 + lo;
            if (v0) contrib[(sbase + 0) * ROUT + oc] = __float2bfloat16(a[0]);
            if (v1) contrib[(sbase + 1) * ROUT + oc] = __float2bfloat16(a[1]);
            if (v2) contrib[(sbase + 2) * ROUT + oc] = __float2bfloat16(a[2]);
            if (v3) contrib[(sbase + 3) * ROUT + oc] = __float2bfloat16(a[3]);
        }

        A0 = P0; A1 = P1;
        P0 = Q0; P1 = Q1;
    }
}

// ---------------------------------------------------------------------------
// Stage 2 (row-sorted, NO atomics on floats): one block per 40-row slice,
// 512 threads. Per chunk: stage src indices, counting-sort them by local row
// in LDS (int atomics for rank), then owner (lr,g) walks ONLY its own row's
// contiguous run, accumulating in registers. One coalesced out write.
// ---------------------------------------------------------------------------
__global__ __launch_bounds__(512)
void stage2_sorted(const __hip_bfloat16* __restrict__ contrib,
                   const unsigned* __restrict__ elist,
                   const int* __restrict__ B,
                   int t, int spr, int capseg,
                   float* __restrict__ out)
{
    __shared__ int kb0[KK], klb[KK];
    __shared__ int koff[KK + 1];
    __shared__ int rowcnt[SLICE];
    __shared__ int rowoff[SLICE + 1];
    __shared__ int srcSorted[CHUNK];

    const int sl  = t * spr + blockIdx.x;  // global slice
    const int tid = threadIdx.x;

    if (tid < KK) {
        const int k = tid;
        const size_t key = (size_t)k * NSLICE + sl;
        const int b0 = B[key];
        const int b1 = B[key + 1];         // sentinel-safe
        const int segb = B[(size_t)k * NSLICE + (size_t)t * spr];
        kb0[k]  = b0;
        klb[k]  = k * capseg + (b0 - segb);
        koff[k] = b1 - b0;                 // counts; prefixed below
    }
    __syncthreads();
    if (tid == 0) {
        int run = 0;
        for (int k = 0; k < KK; ++k) { const int c = koff[k]; koff[k] = run; run += c; }
        koff[KK] = run;
    }
    __syncthreads();
    const int nE = koff[KK];

    const int lr = tid / 12;               // owner row (valid when tid < 480)
    const int g  = tid - lr * 12;          // owner channel octet
    const bool owner = (tid < SLICE * 12);

    f32x4 accA = {0.f, 0.f, 0.f, 0.f};
    f32x4 accB = {0.f, 0.f, 0.f, 0.f};

    for (int c0 = 0; c0 < nE; c0 += CHUNK) {
        const int ce = min(nE - c0, CHUNK);

        if (tid < SLICE) rowcnt[tid] = 0;
        __syncthreads();

        int myLr[2], myRank[2], mySrc[2];
        int nmine = 0;
        for (int i = tid; i < ce; i += 512) {
            const int ge = c0 + i;
            int lo = 0, hi = KK;
            while (hi - lo > 1) {          // binsearch: largest k with koff[k] <= ge
                const int mid = (lo + hi) >> 1;
                if (ge >= koff[mid]) lo = mid; else hi = mid;
            }
            const int j = ge - koff[lo];
            const int l = (int)(elist[kb0[lo] + j] >> 18);
            myLr[nmine]   = l;
            mySrc[nmine]  = klb[lo] + j;
            myRank[nmine] = atomicAdd(&rowcnt[l], 1);   // LDS int atomic
            ++nmine;
        }
        __syncthreads();

        if (tid == 0) {
            int run = 0;
            for (int r = 0; r < SLICE; ++r) { rowoff[r] = run; run += rowcnt[r]; }
            rowoff[SLICE] = run;
        }
        __syncthreads();

        for (int q = 0; q < nmine; ++q)
            srcSorted[rowoff[myLr[q]] + myRank[q]] = mySrc[q];
        __syncthreads();

        if (owner) {
            const int j0 = rowoff[lr], j1 = rowoff[lr + 1];
            for (int j = j0; j < j1; ++j) {
                const bf16x8 v = *reinterpret_cast<const bf16x8*>(
                    contrib + (size_t)srcSorted[j] * ROUT + g * 8);
                accA[0] += bf2f(v[0]); accA[1] += bf2f(v[1]);
                accA[2] += bf2f(v[2]); accA[3] += bf2f(v[3]);
                accB[0] += bf2f(v[4]); accB[1] += bf2f(v[5]);
                accB[2] += bf2f(v[6]); accB[3] += bf2f(v[7]);
            }
        }
        __syncthreads();
    }

    if (owner) {
        float4* o = (float4*)(out + ((size_t)sl * SLICE + lr) * ROUT + g * 8);
        float4 x0 = {accA[0], accA[1], accA[2], accA[3]};
        float4 x1 = {accB[0], accB[1], accB[2], accB[3]};
        o[0] = x0; o[1] = x1;
    }
}

// ---------------------------------------------------------------------------
extern "C" void kernel_launch(void* const* d_in, const int* in_sizes, int n_in,
                              void* d_out, int out_size, void* d_ws, size_t ws_size,
                              hipStream_t stream)
{
    const float* features = (const float*)d_in[0];
    const float* kernel_w = (const float*)d_in[1];
    const int*   in_map   = (const int*)d_in[2];
    const int*   out_map  = (const int*)d_in[3];
    float*       out      = (float*)d_out;

    // workspace layout (256B-aligned)
    const size_t off_L       = 0;                                        // KK*HBLK*NSLICE ints
    const size_t off_B       = off_L + (((size_t)KK * HBLK * NSLICE * 4 + 255) & ~255ul);
    const size_t off_S       = off_B + (((size_t)(NKEY + 1) * 4 + 255) & ~255ul);
    const size_t off_fb      = off_S + 1024;                             // NCB2 ints fits
    const size_t off_wp      = off_fb + (size_t)NN * FROW * 2;           // padded fb 25.6MB
    const size_t off_elist   = off_wp + (size_t)KK * 12 * 64 * 16;
    const size_t off_contrib = off_elist + (((size_t)ETOT + 64) * 4);

    // nt=4: contrib slab 104 MB
    int nt = 0, capseg = 0;
    {
        const size_t need4 = off_contrib + (size_t)KK * 21504 * ROUT * 2;  // ~156 MB
        if (ws_size >= need4) { nt = 4; capseg = 21504; }
    }

    if (nt == 0) {
        hipMemsetAsync(d_out, 0, (size_t)out_size * sizeof(float), stream);
        dim3 grid(FB_BLOCKS_PER_K, KK);
        sparse_conv_scatter<<<grid, 192, 0, stream>>>(features, kernel_w, in_map, out_map, out);
        return;
    }

    const int spr = NSLICE / nt;    // 1250
    const int s1x = 30;             // long streams: ~10 tiles/wave

    char* ws = (char*)d_ws;
    int*      L     = (int*)(ws + off_L);
    int*      B     = (int*)(ws + off_B);
    int*      S     = (int*)(ws + off_S);
    __hip_bfloat16* fb = (__hip_bfloat16*)(ws + off_fb);
    __hip_bfloat16* wp = (__hip_bfloat16*)(ws + off_wp);
    unsigned* elist = (unsigned*)(ws + off_elist);
    __hip_bfloat16* contrib = (__hip_bfloat16*)(ws + off_contrib);

    // precompute (L fully written by hist_pass; out fully written by stage2)
    feat_to_bf16<<<(NN * FROW / 8 + 255) / 256, 256, 0, stream>>>(features, fb);
    build_wpack<<<KK * 12, 64, 0, stream>>>(kernel_w, wp);

    // counting sort by (k, slice):
    //   coalesced histogram -> per-(k,s) blk scan -> flat scan of totals ->
    //   coalesced-staged scatter
    {
        dim3 gh(HBLK, KK);
        hist_pass<<<gh, 256, 0, stream>>>(out_map, L);
    }
    {
        dim3 gb((NSLICE + 255) / 256, KK);
        blk_scan<<<gb, 256, 0, stream>>>(L, B);
    }
    scan_partG<<<NCB2, 256, 0, stream>>>(B, S, NKEY);
    scan_midG<<<1, 256, 0, stream>>>(S, NCB2);
    scan_finalG<<<NCB2, 256, 0, stream>>>(B, S, NKEY, ETOT);
    {
        dim3 gw(HBLK, KK);
        write_elist<<<gw, 256, 0, stream>>>(out_map, in_map, B, L, elist);
    }

    // per range: depth-2-prefetched MFMA into contrib, then row-sorted reduce
    for (int t = 0; t < nt; ++t) {
        dim3 g1(s1x, KK);
        stage1_mfma<<<g1, 256, 0, stream>>>(fb, wp, elist, B, t, spr, capseg, contrib);
        stage2_sorted<<<spr, 512, 0, stream>>>(contrib, elist, B, t, spr, capseg, out);
    }
}

// Round 22
// 343.441 us; speedup vs baseline: 1.0616x; 1.0616x over previous
//
#include <hip/hip_runtime.h>
#include <hip/hip_bf16.h>

// Problem constants (from reference setup_inputs)
#define KK   27
#define MM   80000
#define NN   200000
#define INC  64
#define OUTC 128
#define RIN  48
#define ROUT 96

// output-row slices: 5000 slices x 40 rows; key = k*NSLICE + s (k-major)
#define SLICE   40
#define NSLICE  (NN / SLICE)          // 5000
#define NKEY    (KK * NSLICE)         // 135000

// counting-sort blocking: many blocks for store-concurrency (latency-bound pass)
#define HEPB    2560
#define HBLK    ((MM + HEPB - 1) / HEPB)   // 32 (ceil)
#define ETOT    (KK * MM)             // 2,160,000

// padded bf16 feature row: 64 bf16 = 128 B = exactly 2 cache lines
#define FROW    64

// T-scan geometry (135000 elements)
#define SCHUNK  1024
#define NCB2    ((NKEY + SCHUNK - 1) / SCHUNK)   // 132

#define CHUNK   768                   // stage2 per-chunk entry capacity

typedef __attribute__((ext_vector_type(8))) short bf16x8;  // 8 bf16 = 4 VGPR
typedef __attribute__((ext_vector_type(4))) float f32x4;

__device__ __forceinline__ float bf2f(short s) {
    return __uint_as_float(((unsigned)(unsigned short)s) << 16);
}

// ---------------------------------------------------------------------------
// Fallback: single-pass atomic scatter (R1 kernel, known-good, ~1.66 ms)
// ---------------------------------------------------------------------------
#define FB_BLOCKS_PER_K 200
#define FB_ENTRIES_PER_BLOCK ((MM + FB_BLOCKS_PER_K - 1) / FB_BLOCKS_PER_K)

__global__ __launch_bounds__(192)
void sparse_conv_scatter(const float* __restrict__ feat,
                         const float* __restrict__ w,
                         const int* __restrict__ imap,
                         const int* __restrict__ omap,
                         float* __restrict__ out)
{
    __shared__ float wlds[RIN * ROUT];
    const int k = blockIdx.y;
    const float* wk = w + (size_t)k * INC * OUTC;
    for (int idx = threadIdx.x; idx < RIN * ROUT; idx += 192) {
        int i = idx / ROUT;
        int o = idx - i * ROUT;
        wlds[idx] = wk[i * OUTC + o];
    }
    __syncthreads();

    const int sub = threadIdx.x / 96;
    const int oc  = threadIdx.x % 96;
    const int m0 = blockIdx.x * FB_ENTRIES_PER_BLOCK;
    const int m1 = min(m0 + FB_ENTRIES_PER_BLOCK, MM);
    const int* imk = imap + (size_t)k * MM;
    const int* omk = omap + (size_t)k * MM;

    for (int m = m0 + sub; m < m1; m += 2) {
        const int fin  = imk[m];
        const int fout = omk[m];
        const float4* f4 = (const float4*)(feat + (size_t)fin * RIN);
        float acc = 0.f;
        #pragma unroll
        for (int i4 = 0; i4 < RIN / 4; ++i4) {
            float4 v = f4[i4];
            acc += v.x * wlds[(i4 * 4 + 0) * ROUT + oc];
            acc += v.y * wlds[(i4 * 4 + 1) * ROUT + oc];
            acc += v.z * wlds[(i4 * 4 + 2) * ROUT + oc];
            acc += v.w * wlds[(i4 * 4 + 3) * ROUT + oc];
        }
        atomicAdd(&out[(size_t)fout * ROUT + oc], acc);
    }
}

// ---------------------------------------------------------------------------
// Precompute: features -> bf16 rows PADDED to 128B (zeros in cols 48..63),
// weights -> MFMA B-fragment pack
// ---------------------------------------------------------------------------
__global__ __launch_bounds__(256)
void feat_to_bf16(const float* __restrict__ f, __hip_bfloat16* __restrict__ fb)
{
    const size_t i = (size_t)blockIdx.x * 256 + threadIdx.x;   // one per 8 bf16 out
    if (i >= (size_t)NN * FROW / 8) return;
    const int row = (int)(i >> 3);
    const int c8  = (int)(i & 7);           // 8-bf16 group within padded row
    union { __hip_bfloat16 h[8]; uint4 v; } o;
    if (c8 < 6) {
        const float4* p = (const float4*)(f + (size_t)row * RIN + c8 * 8);
        float4 a = p[0], b = p[1];
        o.h[0] = __float2bfloat16(a.x);
        o.h[1] = __float2bfloat16(a.y);
        o.h[2] = __float2bfloat16(a.z);
        o.h[3] = __float2bfloat16(a.w);
        o.h[4] = __float2bfloat16(b.x);
        o.h[5] = __float2bfloat16(b.y);
        o.h[6] = __float2bfloat16(b.z);
        o.h[7] = __float2bfloat16(b.w);
    } else {
        o.v = make_uint4(0, 0, 0, 0);       // zero pad (k=48..63)
    }
    ((uint4*)fb)[i] = o.v;
}

// wpack: frag f = oct*2 + ktile of kernel k at ((k*12 + f)*64 + lane)*16 bytes
__global__ __launch_bounds__(64)
void build_wpack(const float* __restrict__ w, __hip_bfloat16* __restrict__ wp)
{
    const int b = blockIdx.x;          // k*12 + f
    const int k = b / 12;
    const int f = b % 12;
    const int oct = f / 2, ktile = f % 2;
    const int lane = threadIdx.x;
    const int oc    = oct * 16 + (lane & 15);
    const int kbase = ktile * 32 + (lane >> 4) * 8;
    union { __hip_bfloat16 h[8]; uint4 v; } o;
    #pragma unroll
    for (int j = 0; j < 8; ++j) {
        int ki = kbase + j;
        float val = (ki < RIN) ? w[(size_t)k * INC * OUTC + (size_t)ki * OUTC + oc] : 0.f;
        o.h[j] = __float2bfloat16(val);
    }
    ((uint4*)wp)[(size_t)b * 64 + lane] = o.v;
}

// ---------------------------------------------------------------------------
// Counting sort pass 1: per-(k,block) LDS histogram over slices.
// L layout: L[(k*HBLK + blk)*NSLICE + s]  -> COALESCED writes.
// ---------------------------------------------------------------------------
__global__ __launch_bounds__(256)
void hist_pass(const int* __restrict__ omap, int* __restrict__ L)
{
    __shared__ int h[NSLICE];          // 20 KB
    const int k = blockIdx.y;
    const int blk = blockIdx.x;
    for (int i = threadIdx.x; i < NSLICE; i += 256) h[i] = 0;
    __syncthreads();

    #pragma unroll
    for (int it = 0; it < HEPB / 256; ++it) {
        const int m = blk * HEPB + it * 256 + threadIdx.x;
        if (m < MM) atomicAdd(&h[omap[(size_t)k * MM + m] / SLICE], 1);  // LDS int
    }
    __syncthreads();
    int* row = L + ((size_t)k * HBLK + blk) * NSLICE;
    for (int i = threadIdx.x; i < NSLICE; i += 256) row[i] = h[i];
}

// ---------------------------------------------------------------------------
// blk_scan: per (k,s) column, exclusive prefix over the HBLK blocks (in place)
// and emit bucket total T[k*NSLICE + s]. All accesses coalesced across s.
// ---------------------------------------------------------------------------
__global__ __launch_bounds__(256)
void blk_scan(int* __restrict__ L, int* __restrict__ T)
{
    const int k = blockIdx.y;
    const int s = blockIdx.x * 256 + threadIdx.x;
    if (s >= NSLICE) return;
    int run = 0;
    #pragma unroll
    for (int blk = 0; blk < HBLK; ++blk) {
        const size_t idx = ((size_t)k * HBLK + blk) * NSLICE + s;
        const int v = L[idx];
        L[idx] = run;          // within-(k,s) exclusive offset
        run += v;
    }
    T[(size_t)k * NSLICE + s] = run;   // bucket total
}

// ---------------------------------------------------------------------------
// Generic flat exclusive scan of T[n] (3 kernels). scan_finalG also writes
// the sentinel T[n] = total.
// ---------------------------------------------------------------------------
__global__ __launch_bounds__(256)
void scan_partG(const int* __restrict__ T, int* __restrict__ S, int n)
{
    __shared__ int sh[256];
    const int t = threadIdx.x;
    const int base = blockIdx.x * SCHUNK + t * 4;
    int s = 0;
    #pragma unroll
    for (int j = 0; j < 4; ++j)
        if (base + j < n) s += T[base + j];
    sh[t] = s;
    __syncthreads();
    for (int off = 128; off > 0; off >>= 1) {
        if (t < off) sh[t] += sh[t + off];
        __syncthreads();
    }
    if (t == 0) S[blockIdx.x] = sh[0];
}

__global__ __launch_bounds__(256)
void scan_midG(int* __restrict__ S, int ncb)
{
    __shared__ int sh[256];
    const int t = threadIdx.x;
    const int per = (ncb + 255) / 256;
    const int lo = t * per;
    const int hi = min(lo + per, ncb);
    int tot = 0;
    for (int i = lo; i < hi; ++i) tot += S[i];
    sh[t] = tot;
    __syncthreads();
    for (int off = 1; off < 256; off <<= 1) {
        int x = (t >= off) ? sh[t - off] : 0;
        __syncthreads();
        sh[t] += x;
        __syncthreads();
    }
    int run = sh[t] - tot;    // exclusive base
    for (int i = lo; i < hi; ++i) { const int v = S[i]; S[i] = run; run += v; }
}

__global__ __launch_bounds__(256)
void scan_finalG(int* __restrict__ T, const int* __restrict__ S, int n, int total)
{
    __shared__ int sh[256];
    const int t = threadIdx.x;
    const int base = blockIdx.x * SCHUNK + t * 4;
    int v[4];
    int s = 0;
    #pragma unroll
    for (int j = 0; j < 4; ++j) {
        v[j] = (base + j < n) ? T[base + j] : 0;
        s += v[j];
    }
    sh[t] = s;
    __syncthreads();
    for (int off = 1; off < 256; off <<= 1) {
        int x = (t >= off) ? sh[t - off] : 0;
        __syncthreads();
        sh[t] += x;
        __syncthreads();
    }
    int run = sh[t] - s + S[blockIdx.x];
    #pragma unroll
    for (int j = 0; j < 4; ++j) {
        if (base + j < n) { T[base + j] = run; run += v[j]; }
    }
    if (blockIdx.x == 0 && t == 0) T[n] = total;   // sentinel
}

// ---------------------------------------------------------------------------
// Counting sort pass 2: scatter tagged entries. Single fused LDS cursor:
// slot[s] starts at the global base (B + within-key block offset), and
// atomicAdd returns the global slot directly. 20 KB LDS -> high occupancy.
// elist[slot] = fin | (lr << 18).
// ---------------------------------------------------------------------------
__global__ __launch_bounds__(256)
void write_elist(const int* __restrict__ omap,
                 const int* __restrict__ imap,
                 const int* __restrict__ B,
                 const int* __restrict__ L,
                 unsigned* __restrict__ elist)
{
    __shared__ int slot[NSLICE];       // 20 KB
    const int k = blockIdx.y;
    const int blk = blockIdx.x;

    const int* Bk = B + (size_t)k * NSLICE;
    const int* Lk = L + ((size_t)k * HBLK + blk) * NSLICE;
    for (int i = threadIdx.x; i < NSLICE; i += 256)
        slot[i] = Bk[i] + Lk[i];       // global slot cursor for this block
    __syncthreads();

    #pragma unroll
    for (int it = 0; it < HEPB / 256; ++it) {
        const int m = blk * HEPB + it * 256 + threadIdx.x;
        if (m < MM) {
            const size_t e = (size_t)k * MM + m;
            const int r = omap[e];
            const int s = r / SLICE;
            const int lr = r - s * SLICE;
            const int p = atomicAdd(&slot[s], 1);     // LDS int atomic -> global slot
            elist[p] = (unsigned)imap[e] | ((unsigned)lr << 18);
        }
    }
}

// ---------------------------------------------------------------------------
// Stage 1 (MFMA): per (range,k), stream the contiguous sorted segment as
// 16-entry x 96-oc tiles with DEPTH-2 prefetch; contrib written LINEARLY.
// Feature rows are 128B-aligned (2 lines exactly per gather).
// ---------------------------------------------------------------------------
__global__ __launch_bounds__(256)
void stage1_mfma(const __hip_bfloat16* __restrict__ fb,
                 const __hip_bfloat16* __restrict__ wp,
                 const unsigned* __restrict__ elist,
                 const int* __restrict__ B,
                 int t, int spr, int capseg,
                 __hip_bfloat16* __restrict__ contrib)
{
    const int k = blockIdx.y;
    const int wid  = threadIdx.x >> 6;
    const int lane = threadIdx.x & 63;
    const int lo = lane & 15, hi = lane >> 4;

    const size_t key0 = (size_t)k * NSLICE + (size_t)t * spr;
    const int seg0 = B[key0];
    const int seg1 = B[key0 + spr];          // sentinel covers the end
    const int n = seg1 - seg0;
    const int ntiles = (n + 15) >> 4;

    bf16x8 Bf[12];
    #pragma unroll
    for (int f = 0; f < 12; ++f)
        Bf[f] = *reinterpret_cast<const bf16x8*>(
            (const char*)wp + (((size_t)k * 12 + f) * 64 + lane) * 16);

    const int wstride = gridDim.x * 4;
    const int t0 = blockIdx.x * 4 + wid;
    if (t0 >= ntiles) return;

    auto LOADA = [&](int tile, bf16x8& a0, bf16x8& a1) {
        const int ea = seg0 + tile * 16 + lo;
        const unsigned tg = (tile < ntiles && ea < seg1) ? elist[ea] : 0u;
        const size_t rb = (size_t)(tg & 0x3FFFFu) * (FROW * 2);   // 128B rows
        a0 = *reinterpret_cast<const bf16x8*>((const char*)fb + rb + hi * 16);
        a1 = *reinterpret_cast<const bf16x8*>((const char*)fb + rb + 64 + hi * 16);
    };

    bf16x8 A0, A1, P0, P1, Q0, Q1;
    LOADA(t0, A0, A1);
    LOADA(t0 + wstride, P0, P1);

    for (int tile = t0; tile < ntiles; tile += wstride) {
        LOADA(tile + 2 * wstride, Q0, Q1);   // depth-2 prefetch

        const int e4 = tile * 16 + hi * 4;      // segment-local entry index base
        const size_t sbase = (size_t)k * capseg + e4;
        const bool v0 = (e4 + 0) < n, v1 = (e4 + 1) < n,
                   v2 = (e4 + 2) < n, v3 = (e4 + 3) < n;

        #pragma unroll
        for (int oct = 0; oct < 6; ++oct) {
            f32x4 a = {0.f, 0.f, 0.f, 0.f};
            a = __builtin_amdgcn_mfma_f32_16x16x32_bf16(A0, Bf[oct * 2 + 0], a, 0, 0, 0);
            a = __builtin_amdgcn_mfma_f32_16x16x32_bf16(A1, Bf[oct * 2 + 1], a, 0, 0, 0);
            const int oc = oct * 16 + lo;
            if (v0) contrib[(sbase + 0) * ROUT + oc] = __float2bfloat16(a[0]);
            if (v1) contrib[(sbase + 1) * ROUT + oc] = __float2bfloat16(a[1]);
            if (v2) contrib[(sbase + 2) * ROUT + oc] = __float2bfloat16(a[2]);
            if (v3) contrib[(sbase + 3) * ROUT + oc] = __float2bfloat16(a[3]);
        }

        A0 = P0; A1 = P1;
        P0 = Q0; P1 = Q1;
    }
}

// ---------------------------------------------------------------------------
// Stage 2 (row-sorted, NO atomics on floats): one block per 40-row slice,
// 512 threads. Per chunk: stage src indices, counting-sort them by local row
// in LDS (int atomics for rank), then owner (lr,g) walks ONLY its own row's
// contiguous run, accumulating in registers. One coalesced out write.
// ---------------------------------------------------------------------------
__global__ __launch_bounds__(512)
void stage2_sorted(const __hip_bfloat16* __restrict__ contrib,
                   const unsigned* __restrict__ elist,
                   const int* __restrict__ B,
                   int t, int spr, int capseg,
                   float* __restrict__ out)
{
    __shared__ int kb0[KK], klb[KK];
    __shared__ int koff[KK + 1];
    __shared__ int rowcnt[SLICE];
    __shared__ int rowoff[SLICE + 1];
    __shared__ int srcSorted[CHUNK];

    const int sl  = t * spr + blockIdx.x;  // global slice
    const int tid = threadIdx.x;

    if (tid < KK) {
        const int k = tid;
        const size_t key = (size_t)k * NSLICE + sl;
        const int b0 = B[key];
        const int b1 = B[key + 1];         // sentinel-safe
        const int segb = B[(size_t)k * NSLICE + (size_t)t * spr];
        kb0[k]  = b0;
        klb[k]  = k * capseg + (b0 - segb);
        koff[k] = b1 - b0;                 // counts; prefixed below
    }
    __syncthreads();
    if (tid == 0) {
        int run = 0;
        for (int k = 0; k < KK; ++k) { const int c = koff[k]; koff[k] = run; run += c; }
        koff[KK] = run;
    }
    __syncthreads();
    const int nE = koff[KK];

    const int lr = tid / 12;               // owner row (valid when tid < 480)
    const int g  = tid - lr * 12;          // owner channel octet
    const bool owner = (tid < SLICE * 12);

    f32x4 accA = {0.f, 0.f, 0.f, 0.f};
    f32x4 accB = {0.f, 0.f, 0.f, 0.f};

    for (int c0 = 0; c0 < nE; c0 += CHUNK) {
        const int ce = min(nE - c0, CHUNK);

        if (tid < SLICE) rowcnt[tid] = 0;
        __syncthreads();

        int myLr[2], myRank[2], mySrc[2];
        int nmine = 0;
        for (int i = tid; i < ce; i += 512) {
            const int ge = c0 + i;
            int lo = 0, hi = KK;
            while (hi - lo > 1) {          // binsearch: largest k with koff[k] <= ge
                const int mid = (lo + hi) >> 1;
                if (ge >= koff[mid]) lo = mid; else hi = mid;
            }
            const int j = ge - koff[lo];
            const int l = (int)(elist[kb0[lo] + j] >> 18);
            myLr[nmine]   = l;
            mySrc[nmine]  = klb[lo] + j;
            myRank[nmine] = atomicAdd(&rowcnt[l], 1);   // LDS int atomic
            ++nmine;
        }
        __syncthreads();

        if (tid == 0) {
            int run = 0;
            for (int r = 0; r < SLICE; ++r) { rowoff[r] = run; run += rowcnt[r]; }
            rowoff[SLICE] = run;
        }
        __syncthreads();

        for (int q = 0; q < nmine; ++q)
            srcSorted[rowoff[myLr[q]] + myRank[q]] = mySrc[q];
        __syncthreads();

        if (owner) {
            const int j0 = rowoff[lr], j1 = rowoff[lr + 1];
            for (int j = j0; j < j1; ++j) {
                const bf16x8 v = *reinterpret_cast<const bf16x8*>(
                    contrib + (size_t)srcSorted[j] * ROUT + g * 8);
                accA[0] += bf2f(v[0]); accA[1] += bf2f(v[1]);
                accA[2] += bf2f(v[2]); accA[3] += bf2f(v[3]);
                accB[0] += bf2f(v[4]); accB[1] += bf2f(v[5]);
                accB[2] += bf2f(v[6]); accB[3] += bf2f(v[7]);
            }
        }
        __syncthreads();
    }

    if (owner) {
        float4* o = (float4*)(out + ((size_t)sl * SLICE + lr) * ROUT + g * 8);
        float4 x0 = {accA[0], accA[1], accA[2], accA[3]};
        float4 x1 = {accB[0], accB[1], accB[2], accB[3]};
        o[0] = x0; o[1] = x1;
    }
}

// ---------------------------------------------------------------------------
extern "C" void kernel_launch(void* const* d_in, const int* in_sizes, int n_in,
                              void* d_out, int out_size, void* d_ws, size_t ws_size,
                              hipStream_t stream)
{
    const float* features = (const float*)d_in[0];
    const float* kernel_w = (const float*)d_in[1];
    const int*   in_map   = (const int*)d_in[2];
    const int*   out_map  = (const int*)d_in[3];
    float*       out      = (float*)d_out;

    // workspace layout (256B-aligned)
    const size_t off_L       = 0;                                        // KK*HBLK*NSLICE ints
    const size_t off_B       = off_L + (((size_t)KK * HBLK * NSLICE * 4 + 255) & ~255ul);
    const size_t off_S       = off_B + (((size_t)(NKEY + 1) * 4 + 255) & ~255ul);
    const size_t off_fb      = off_S + 1024;                             // NCB2 ints fits
    const size_t off_wp      = off_fb + (size_t)NN * FROW * 2;           // padded fb 25.6MB
    const size_t off_elist   = off_wp + (size_t)KK * 12 * 64 * 16;
    const size_t off_contrib = off_elist + (((size_t)ETOT + 64) * 4);

    // nt=4: contrib slab 104 MB
    int nt = 0, capseg = 0;
    {
        const size_t need4 = off_contrib + (size_t)KK * 21504 * ROUT * 2;  // ~160 MB
        if (ws_size >= need4) { nt = 4; capseg = 21504; }
    }

    if (nt == 0) {
        hipMemsetAsync(d_out, 0, (size_t)out_size * sizeof(float), stream);
        dim3 grid(FB_BLOCKS_PER_K, KK);
        sparse_conv_scatter<<<grid, 192, 0, stream>>>(features, kernel_w, in_map, out_map, out);
        return;
    }

    const int spr = NSLICE / nt;    // 1250
    const int s1x = 60;             // stage1 blocks per k per range (R19 config)

    char* ws = (char*)d_ws;
    int*      L     = (int*)(ws + off_L);
    int*      B     = (int*)(ws + off_B);
    int*      S     = (int*)(ws + off_S);
    __hip_bfloat16* fb = (__hip_bfloat16*)(ws + off_fb);
    __hip_bfloat16* wp = (__hip_bfloat16*)(ws + off_wp);
    unsigned* elist = (unsigned*)(ws + off_elist);
    __hip_bfloat16* contrib = (__hip_bfloat16*)(ws + off_contrib);

    // precompute (L fully written by hist_pass; out fully written by stage2)
    feat_to_bf16<<<(NN * FROW / 8 + 255) / 256, 256, 0, stream>>>(features, fb);
    build_wpack<<<KK * 12, 64, 0, stream>>>(kernel_w, wp);

    // counting sort by (k, slice):
    //   coalesced histogram -> per-(k,s) blk scan -> flat scan of totals ->
    //   fused-cursor scatter
    {
        dim3 gh(HBLK, KK);
        hist_pass<<<gh, 256, 0, stream>>>(out_map, L);
    }
    {
        dim3 gb((NSLICE + 255) / 256, KK);
        blk_scan<<<gb, 256, 0, stream>>>(L, B);
    }
    scan_partG<<<NCB2, 256, 0, stream>>>(B, S, NKEY);
    scan_midG<<<1, 256, 0, stream>>>(S, NCB2);
    scan_finalG<<<NCB2, 256, 0, stream>>>(B, S, NKEY, ETOT);
    {
        dim3 gw(HBLK, KK);
        write_elist<<<gw, 256, 0, stream>>>(out_map, in_map, B, L, elist);
    }

    // per range: depth-2-prefetched MFMA into contrib, then row-sorted reduce
    for (int t = 0; t < nt; ++t) {
        dim3 g1(s1x, KK);
        stage1_mfma<<<g1, 256, 0, stream>>>(fb, wp, elist, B, t, spr, capseg, contrib);
        stage2_sorted<<<spr, 512, 0, stream>>>(contrib, elist, B, t, spr, capseg, out);
    }
}